// Round 8
// baseline (658.779 us; speedup 1.0000x reference)
//
#include <hip/hip_runtime.h>
#include <hip/hip_cooperative_groups.h>
#include <math.h>

namespace cg = cooperative_groups;

// ---------------- sizes ----------------
#define Bn 8
#define Wn 20
#define Mn 512
#define Fn 16
#define Hn 128

typedef __attribute__((ext_vector_type(8))) short short8;
typedef __attribute__((ext_vector_type(4))) float f32x4;
typedef unsigned short ushort_t;

__device__ __forceinline__ float sigmoidf_(float x) {
  return 1.0f / (1.0f + __expf(-x));
}
__device__ __forceinline__ float tanhf_(float x) {
  float xx = fminf(fmaxf(x, -15.f), 15.f);
  float e = __expf(2.f * xx);
  return (e - 1.f) / (e + 1.f);
}
__device__ __forceinline__ float reluf_(float x) { return fmaxf(x, 0.f); }
__device__ __forceinline__ float eluf_(float x) {
  return (x > 0.f) ? x : (__expf(x) - 1.f);
}
__device__ __forceinline__ ushort_t bf16_rne(float v) {
  unsigned u = __float_as_uint(v);
  u += 0x7FFFu + ((u >> 16) & 1u);
  return (ushort_t)(u >> 16);
}
__device__ __forceinline__ float bf16_to_f(ushort_t b) {
  return __uint_as_float(((unsigned)b) << 16);
}

struct KArgs {
  const float *X, *Y, *adj, *V, *bv, *W1, *b1, *W2, *Wb, *wb;
  const float *conv_w, *conv_b, *convl_w, *convl_b;
  const float *gWih, *gWhh, *gbih, *gbhh;
  const float *gc1_W, *gc1_b, *gc2_W, *gc2_b, *out_W, *out_b;
  const float *Y2;
  float *out, *lhid, *p1, *p2, *amx, *ssq, *Abuf, *t2;
  ushort_t *Bpack, *WbT_hi, *WbT_lo, *t1T_hi, *t1T_lo;
};

#define LDK 168
#define HSZ (16 * LDK)
#define CPK 40
#define SMEM_BYTES 41984

__global__ __launch_bounds__(512, 2) void mega_kernel(KArgs a) {
  cg::grid_group grid = cg::this_grid();
  const int tid = threadIdx.x;
  const int blk = blockIdx.x;
  const int wave = tid >> 6;
  const int lane = tid & 63;
  const int quad = lane >> 4;
  const int jl = lane & 15;
  __shared__ __align__(16) char smem_u[SMEM_BYTES];

  // ================= P0: pack GRU weights + WbT split + conv_t1 + zero =======
  {
    int gid = blk * 512 + tid;
    if (gid < 4096) a.ssq[gid] = 0.f;
    if (gid == 0) a.out[0] = 0.f;
    if (gid < 24 * 5 * 512) {
      int j = gid & 7;
      int ln = (gid >> 3) & 63;
      int ks = (gid >> 9) % 5;
      int nt = gid / (5 * 512);
      int k = ks * 32 + (ln >> 4) * 8 + j;
      int g = (nt & 7) * 16 + (nt >> 3) * 128 + (ln & 15);
      float val = 0.f;
      if (k < 128) val = a.gWhh[g * 128 + k];
      else if (k < 144) val = a.gWih[g * 16 + (k - 128)];
      ushort_t hb = bf16_rne(val);
      a.Bpack[(((long)nt * 5 + ks) * 2 + 0) * 512 + ln * 8 + j] = hb;
      a.Bpack[(((long)nt * 5 + ks) * 2 + 1) * 512 + ln * 8 + j] =
          bf16_rne(val - bf16_to_f(hb));
    }
    // ---- conv + t1 (16 nodes per block) ----
    float* xs  = (float*)smem_u;                 // 16*16*20
    float* cw  = (float*)(smem_u + 20480);       // 3200
    float* clw = (float*)(smem_u + 33280);       // 1600
    float* rs  = (float*)(smem_u + 39680);       // 16*32
    int n0 = blk * 16;
    int b = n0 >> 9, m0 = n0 & 511;
    for (int idx = tid; idx < 3200; idx += 512) cw[idx] = a.conv_w[idx];
    for (int idx = tid; idx < 1600; idx += 512) clw[idx] = a.convl_w[idx];
    if (tid < 256) {
      int s = tid >> 4, f = tid & 15;
      for (int w = 0; w < 20; ++w)
        xs[(s * 16 + f) * 20 + w] = a.X[((long)(b * 20 + w) * 512 + m0) * 16 + tid];
    }
    __syncthreads();
    if (tid < 160) {
      int s = tid / 10, k = tid % 10;
      float a0 = a.conv_b[k];
      float l0 = a.convl_b[k], l1 = a.convl_b[k];
      for (int f = 0; f < 16; ++f) {
#pragma unroll
        for (int w = 0; w < 20; ++w)
          a0 = fmaf(xs[(s * 16 + f) * 20 + w], cw[k * 320 + f * 20 + w], a0);
#pragma unroll
        for (int q = 0; q < 10; ++q) {
          float wv = clw[k * 160 + f * 10 + q];
          l0 = fmaf(xs[(s * 16 + f) * 20 + 2 * q], wv, l0);
          l1 = fmaf(xs[(s * 16 + f) * 20 + 2 * q + 1], wv, l1);
        }
      }
      rs[s * 32 + k * 3 + 0] = reluf_(a0);
      rs[s * 32 + k * 3 + 1] = reluf_(l0);
      rs[s * 32 + k * 3 + 2] = reluf_(l1);
    }
    __syncthreads();
    {
      int col = tid & 127, grp = tid >> 7;
      float w[30];
#pragma unroll
      for (int q = 0; q < 30; ++q) w[q] = a.gc1_W[q * 128 + col];
      long base = ((long)b * 128 + col) * 512 + m0;
#pragma unroll
      for (int ss = 0; ss < 4; ++ss) {
        int s = grp * 4 + ss;
        float acc = 0.f;
#pragma unroll
        for (int q = 0; q < 30; ++q) acc = fmaf(rs[s * 32 + q], w[q], acc);
        ushort_t hb = bf16_rne(acc);
        a.t1T_hi[base + s] = hb;
        a.t1T_lo[base + s] = bf16_rne(acc - bf16_to_f(hb));
      }
    }
    // ---- WbT transpose+split (blocks 0..63) ----
    if (blk < 64) {
      __syncthreads();
      float* wt = (float*)smem_u;                // 64*65
      int k0 = (blk >> 3) * 64, j0w = (blk & 7) * 64;
      for (int idx = tid; idx < 4096; idx += 512) {
        int r = idx >> 6, c = idx & 63;
        wt[r * 65 + c] = a.Wb[(long)(k0 + r) * 512 + j0w + c];
      }
      __syncthreads();
      for (int idx = tid; idx < 4096; idx += 512) {
        int r = idx >> 6, c = idx & 63;
        float v = wt[c * 65 + r];
        ushort_t hb = bf16_rne(v);
        a.WbT_hi[(long)(j0w + r) * 512 + k0 + c] = hb;
        a.WbT_lo[(long)(j0w + r) * 512 + k0 + c] = bf16_rne(v - bf16_to_f(hb));
      }
    }
  }
  __threadfence();
  grid.sync();

  // ================= P1: GRU + fused p1/p2 epilogue ==========================
  {
    ushort_t* smem_hs = (ushort_t*)smem_u;
    const int j0 = wave * 16;
    const int b = blk >> 5;
    const int m0 = (blk & 31) * 16;

    short8 frR[5][2], frZ[5][2], frN[4][2], frXN[2];
#pragma unroll
    for (int ks = 0; ks < 5; ++ks)
#pragma unroll
      for (int p = 0; p < 2; ++p) {
        frR[ks][p] = *(const short8*)&a.Bpack[(((long)(wave) * 5 + ks) * 2 + p) * 512 + lane * 8];
        frZ[ks][p] = *(const short8*)&a.Bpack[(((long)(8 + wave) * 5 + ks) * 2 + p) * 512 + lane * 8];
      }
#pragma unroll
    for (int ks = 0; ks < 4; ++ks)
#pragma unroll
      for (int p = 0; p < 2; ++p)
        frN[ks][p] = *(const short8*)&a.Bpack[(((long)(16 + wave) * 5 + ks) * 2 + p) * 512 + lane * 8];
#pragma unroll
    for (int p = 0; p < 2; ++p)
      frXN[p] = *(const short8*)&a.Bpack[(((long)(16 + wave) * 5 + 4) * 2 + p) * 512 + lane * 8];

    const float cr  = a.gbih[j0 + jl] + a.gbhh[j0 + jl];
    const float cz  = a.gbih[128 + j0 + jl] + a.gbhh[128 + j0 + jl];
    const float cnx = a.gbih[256 + j0 + jl];
    const float cnh = a.gbhh[256 + j0 + jl];

    for (int i = tid; i < 4 * HSZ; i += 512) smem_hs[i] = 0;

    const float* Xb = a.X + (long)b * (Wn * Mn * Fn) + (long)m0 * Fn;
    float x0 = 0.f;
    if (tid < 256) x0 = Xb[tid];
    __syncthreads();
    if (tid < 256) {
      int s = tid >> 4, f = tid & 15;
      ushort_t hb = bf16_rne(x0);
      smem_hs[0 * HSZ + s * LDK + 128 + f] = hb;
      smem_hs[2 * HSZ + s * LDK + 128 + f] = bf16_rne(x0 - bf16_to_f(hb));
    }
    __syncthreads();

    float hp[4] = {0.f, 0.f, 0.f, 0.f};
    for (int t = 0; t < Wn; ++t) {
      const int cur = t & 1, nxt = cur ^ 1;
      const int hiC = cur * HSZ, loC = (2 + cur) * HSZ;
      const int hiN = nxt * HSZ, loN = (2 + nxt) * HSZ;
      float xpre = 0.f;
      if (tid < 256 && t < Wn - 1) xpre = Xb[(long)(t + 1) * (Mn * Fn) + tid];

      f32x4 aR[2], aZ[2], aHN[2], aXN;
      aR[0] = aR[1] = aZ[0] = aZ[1] = aHN[0] = aHN[1] = aXN = (f32x4){0.f, 0.f, 0.f, 0.f};
#pragma unroll
      for (int ks = 0; ks < 5; ++ks) {
        const int p = ks & 1;
        short8 ah = *(const short8*)&smem_hs[hiC + jl * LDK + ks * 32 + quad * 8];
        short8 al = *(const short8*)&smem_hs[loC + jl * LDK + ks * 32 + quad * 8];
        aR[p] = __builtin_amdgcn_mfma_f32_16x16x32_bf16(ah, frR[ks][0], aR[p], 0, 0, 0);
        aR[p] = __builtin_amdgcn_mfma_f32_16x16x32_bf16(ah, frR[ks][1], aR[p], 0, 0, 0);
        aR[p] = __builtin_amdgcn_mfma_f32_16x16x32_bf16(al, frR[ks][0], aR[p], 0, 0, 0);
        aZ[p] = __builtin_amdgcn_mfma_f32_16x16x32_bf16(ah, frZ[ks][0], aZ[p], 0, 0, 0);
        aZ[p] = __builtin_amdgcn_mfma_f32_16x16x32_bf16(ah, frZ[ks][1], aZ[p], 0, 0, 0);
        aZ[p] = __builtin_amdgcn_mfma_f32_16x16x32_bf16(al, frZ[ks][0], aZ[p], 0, 0, 0);
        if (ks < 4) {
          aHN[p] = __builtin_amdgcn_mfma_f32_16x16x32_bf16(ah, frN[ks][0], aHN[p], 0, 0, 0);
          aHN[p] = __builtin_amdgcn_mfma_f32_16x16x32_bf16(ah, frN[ks][1], aHN[p], 0, 0, 0);
          aHN[p] = __builtin_amdgcn_mfma_f32_16x16x32_bf16(al, frN[ks][0], aHN[p], 0, 0, 0);
        } else {
          aXN = __builtin_amdgcn_mfma_f32_16x16x32_bf16(ah, frXN[0], aXN, 0, 0, 0);
          aXN = __builtin_amdgcn_mfma_f32_16x16x32_bf16(ah, frXN[1], aXN, 0, 0, 0);
          aXN = __builtin_amdgcn_mfma_f32_16x16x32_bf16(al, frXN[0], aXN, 0, 0, 0);
        }
      }
#pragma unroll
      for (int reg = 0; reg < 4; ++reg) {
        float r = sigmoidf_(aR[0][reg] + aR[1][reg] + cr);
        float z = sigmoidf_(aZ[0][reg] + aZ[1][reg] + cz);
        float n = tanhf_(aXN[reg] + cnx + r * (aHN[0][reg] + aHN[1][reg] + cnh));
        float h = (1.f - z) * n + z * hp[reg];
        hp[reg] = h;
        int s = quad * 4 + reg;
        ushort_t hb = bf16_rne(h);
        smem_hs[hiN + s * LDK + j0 + jl] = hb;
        smem_hs[loN + s * LDK + j0 + jl] = bf16_rne(h - bf16_to_f(hb));
      }
      if (tid < 256 && t < Wn - 1) {
        int s = tid >> 4, f = tid & 15;
        ushort_t hb = bf16_rne(xpre);
        smem_hs[hiN + s * LDK + 128 + f] = hb;
        smem_hs[loN + s * LDK + 128 + f] = bf16_rne(xpre - bf16_to_f(hb));
      }
      __syncthreads();
    }

    float* hs_f = (float*)smem_u;
#pragma unroll
    for (int reg = 0; reg < 4; ++reg) {
      int s = quad * 4 + reg;
      float h = hp[reg];
      a.lhid[(long)(blk * 16 + s) * Hn + j0 + jl] = h;
      hs_f[s * 132 + j0 + jl] = h;
    }
    __syncthreads();
    {
      int k = tid & 63;
      int part = (tid >> 6) & 1;
      int sg = tid >> 7;
      const float* Wp = part ? a.W2 : a.W1;
      float acc[4];
      float init = part ? 0.f : a.b1[k];
      acc[0] = acc[1] = acc[2] = acc[3] = init;
      for (int h = 0; h < 128; h += 4) {
        float4 w = *(const float4*)&Wp[k * 128 + h];
#pragma unroll
        for (int rr = 0; rr < 4; ++rr) {
          float4 q = *(const float4*)&hs_f[(sg * 4 + rr) * 132 + h];
          acc[rr] += q.x * w.x + q.y * w.y + q.z * w.z + q.w * w.w;
        }
      }
      float* outp = part ? a.p2 : a.p1;
#pragma unroll
      for (int rr = 0; rr < 4; ++rr)
        outp[(long)(blk * 16 + sg * 4 + rr) * 64 + k] = acc[rr];
    }
  }
  __threadfence();
  grid.sync();

  // ================= P2: amx (8 tiles/block: 4 passes x 2 halves) ============
  {
    float* Vs   = (float*)smem_u;                  // 64
    float* p1s  = (float*)(smem_u + 256);          // 2 x 32 x 68
    float* p2s  = (float*)(smem_u + 256 + 17408);  // 2 x 32 x 68
    float* cred = (float*)(smem_u + 256 + 34816);  // 2 x 16 x 33
    int half = tid >> 8, t = tid & 255;
    if (tid < 64) Vs[tid] = a.V[tid];
    float* P1 = p1s + half * 2176;
    float* P2 = p2s + half * 2176;
    float* CR = cred + half * 528;
    for (int pass = 0; pass < 4; ++pass) {
      int tile = blk * 8 + pass * 2 + half;
      int bz = tile >> 8, by = (tile >> 4) & 15, bx = tile & 15;
      int i0 = by * 32, j0 = bx * 32;
      __syncthreads();
      {
        int rr = t >> 3, c0 = (t & 7) * 8;
        *(float4*)&P1[rr * 68 + c0]     = *(const float4*)&a.p1[(long)(bz * 512 + j0 + rr) * 64 + c0];
        *(float4*)&P1[rr * 68 + c0 + 4] = *(const float4*)&a.p1[(long)(bz * 512 + j0 + rr) * 64 + c0 + 4];
        *(float4*)&P2[rr * 68 + c0]     = *(const float4*)&a.p2[(long)(bz * 512 + i0 + rr) * 64 + c0];
        *(float4*)&P2[rr * 68 + c0 + 4] = *(const float4*)&a.p2[(long)(bz * 512 + i0 + rr) * 64 + c0 + 4];
      }
      __syncthreads();
      int r0 = t >> 4, c0 = t & 15;
      float acc[2][2] = {{0.f, 0.f}, {0.f, 0.f}};
      for (int k = 0; k < 64; ++k) {
        float vj0 = P1[c0 * 68 + k], vj1 = P1[(c0 + 16) * 68 + k];
        float vi0 = P2[r0 * 68 + k], vi1 = P2[(r0 + 16) * 68 + k];
        float vk = Vs[k];
        acc[0][0] = fmaf(eluf_(vj0 + vi0), vk, acc[0][0]);
        acc[0][1] = fmaf(eluf_(vj1 + vi0), vk, acc[0][1]);
        acc[1][0] = fmaf(eluf_(vj0 + vi1), vk, acc[1][0]);
        acc[1][1] = fmaf(eluf_(vj1 + vi1), vk, acc[1][1]);
      }
      float bvv = a.bv[0];
      float s2[2] = {0.f, 0.f};
#pragma unroll
      for (int aa = 0; aa < 2; ++aa)
#pragma unroll
        for (int c = 0; c < 2; ++c) {
          float v = acc[aa][c] + bvv;
          a.amx[((long)(bz * 512 + i0 + r0 + aa * 16)) * 512 + j0 + c0 + c * 16] = v;
          s2[c] += v * v;
        }
      CR[r0 * 33 + c0] = s2[0];
      CR[r0 * 33 + c0 + 16] = s2[1];
      __syncthreads();
      if (t < 32) {
        float s = 0.f;
#pragma unroll
        for (int p = 0; p < 16; ++p) s += CR[p * 33 + t];
        atomicAdd(&a.ssq[bz * 512 + j0 + t], s);
      }
    }
  }
  __threadfence();
  grid.sync();

  // ================= P3: gemm_cA (split-bf16 MFMA, 8 waves) ==================
  {
    ushort_t* Ahi = (ushort_t*)smem_u;                // 128 x CPK
    ushort_t* Alo = (ushort_t*)(smem_u + 10240);
    ushort_t* Bhi = (ushort_t*)(smem_u + 20480);      // 64 x CPK
    ushort_t* Blo = (ushort_t*)(smem_u + 25600);
    float*    rsS = (float*)(smem_u + 30720);         // 512
    int bx = blk & 7, by = (blk >> 3) & 3, bz = blk >> 5;
    int i0 = by * 128, j0 = bx * 64;
    const float* Abase = a.amx + (long)bz * 262144;
    const float* sb = a.ssq + bz * 512;
    rsS[tid] = 1.f / fmaxf(sqrtf(sb[tid]), 1e-12f);

    f32x4 acc[4];
#pragma unroll
    for (int c = 0; c < 4; ++c) acc[c] = (f32x4){0.f, 0.f, 0.f, 0.f};

    for (int kk0 = 0; kk0 < 512; kk0 += 32) {
      __syncthreads();
#pragma unroll
      for (int l = 0; l < 2; ++l) {
        int e = l * 2048 + tid * 4;
        int r = e >> 5, kq = e & 31;
        float4 v = *(const float4*)&Abase[(long)(i0 + r) * 512 + kk0 + kq];
        float4 sc = *(const float4*)&rsS[kk0 + kq];
        float vv[4] = {v.x * sc.x, v.y * sc.y, v.z * sc.z, v.w * sc.w};
#pragma unroll
        for (int q = 0; q < 4; ++q) {
          ushort_t hb = bf16_rne(vv[q]);
          Ahi[r * CPK + kq + q] = hb;
          Alo[r * CPK + kq + q] = bf16_rne(vv[q] - bf16_to_f(hb));
        }
      }
      if (tid < 256) {
        int e = tid * 8;
        int r = e >> 5, kc = e & 31;
        *(uint4*)&Bhi[r * CPK + kc] = *(const uint4*)&a.WbT_hi[(long)(j0 + r) * 512 + kk0 + kc];
        *(uint4*)&Blo[r * CPK + kc] = *(const uint4*)&a.WbT_lo[(long)(j0 + r) * 512 + kk0 + kc];
      }
      __syncthreads();
      short8 ah = *(const short8*)&Ahi[(wave * 16 + jl) * CPK + quad * 8];
      short8 al = *(const short8*)&Alo[(wave * 16 + jl) * CPK + quad * 8];
      short8 bh[4], bl[4];
#pragma unroll
      for (int tn = 0; tn < 4; ++tn) {
        bh[tn] = *(const short8*)&Bhi[(tn * 16 + jl) * CPK + quad * 8];
        bl[tn] = *(const short8*)&Blo[(tn * 16 + jl) * CPK + quad * 8];
      }
#pragma unroll
      for (int tn = 0; tn < 4; ++tn) {
        acc[tn] = __builtin_amdgcn_mfma_f32_16x16x32_bf16(ah, bh[tn], acc[tn], 0, 0, 0);
        acc[tn] = __builtin_amdgcn_mfma_f32_16x16x32_bf16(ah, bl[tn], acc[tn], 0, 0, 0);
        acc[tn] = __builtin_amdgcn_mfma_f32_16x16x32_bf16(al, bh[tn], acc[tn], 0, 0, 0);
      }
    }
    const float wbv = a.wb[0];
#pragma unroll
    for (int tn = 0; tn < 4; ++tn) {
      int j = j0 + tn * 16 + jl;
      float sj = rsS[j];
#pragma unroll
      for (int reg = 0; reg < 4; ++reg) {
        int i = i0 + wave * 16 + quad * 4 + reg;
        long ofs = (long)bz * 262144 + (long)i * 512 + j;
        float c = sigmoidf_(acc[tn][reg] + wbv);
        float am = Abase[(long)i * 512 + j] * sj;
        float ad = a.adj[(long)i * 512 + j];
        a.Abuf[ofs] = ad * c + am * (1.f - c);
      }
    }
  }
  __threadfence();
  grid.sync();

  // ================= P4: gemm_h1 + fused t2 ==================================
  {
    ushort_t* Ahi = (ushort_t*)smem_u;                // 16 x CPK
    ushort_t* Alo = (ushort_t*)(smem_u + 1280);
    ushort_t* Bhi = (ushort_t*)(smem_u + 2560);       // 128 x CPK
    ushort_t* Blo = (ushort_t*)(smem_u + 12800);
    float*    h1s = (float*)(smem_u + 23040);         // 16 x 132
    float*    gw  = (float*)(smem_u + 31488);         // 1280
    int ib = blk & 31, bz = blk >> 5;
    int i0 = ib * 16;
    const float* Ab = a.Abuf + (long)bz * 262144;
    for (int idx = tid; idx < 1280; idx += 512) gw[idx] = a.gc2_W[idx];

    f32x4 acc[2];
    acc[0] = acc[1] = (f32x4){0.f, 0.f, 0.f, 0.f};
    for (int kk0 = 0; kk0 < 512; kk0 += 32) {
      __syncthreads();
      {
        int r = tid >> 5, kq = tid & 31;
        float v = Ab[(long)(i0 + r) * 512 + kk0 + kq];
        ushort_t hb = bf16_rne(v);
        Ahi[r * CPK + kq] = hb;
        Alo[r * CPK + kq] = bf16_rne(v - bf16_to_f(hb));
      }
      {
        int e = tid * 8;
        int r = e >> 5, kc = e & 31;
        *(uint4*)&Bhi[r * CPK + kc] = *(const uint4*)&a.t1T_hi[((long)bz * 128 + r) * 512 + kk0 + kc];
        *(uint4*)&Blo[r * CPK + kc] = *(const uint4*)&a.t1T_lo[((long)bz * 128 + r) * 512 + kk0 + kc];
      }
      __syncthreads();
      if (wave < 4) {
        short8 ah = *(const short8*)&Ahi[jl * CPK + quad * 8];
        short8 al = *(const short8*)&Alo[jl * CPK + quad * 8];
#pragma unroll
        for (int tn = 0; tn < 2; ++tn) {
          short8 bh = *(const short8*)&Bhi[(wave * 32 + tn * 16 + jl) * CPK + quad * 8];
          short8 bl = *(const short8*)&Blo[(wave * 32 + tn * 16 + jl) * CPK + quad * 8];
          acc[tn] = __builtin_amdgcn_mfma_f32_16x16x32_bf16(ah, bh, acc[tn], 0, 0, 0);
          acc[tn] = __builtin_amdgcn_mfma_f32_16x16x32_bf16(ah, bl, acc[tn], 0, 0, 0);
          acc[tn] = __builtin_amdgcn_mfma_f32_16x16x32_bf16(al, bh, acc[tn], 0, 0, 0);
        }
      }
    }
    __syncthreads();
    if (wave < 4) {
#pragma unroll
      for (int tn = 0; tn < 2; ++tn) {
        int n = wave * 32 + tn * 16 + jl;
        float bb = a.gc1_b[n];
#pragma unroll
        for (int reg = 0; reg < 4; ++reg) {
          int r = quad * 4 + reg;
          h1s[r * 132 + n] = reluf_(acc[tn][reg] + bb);
        }
      }
    }
    __syncthreads();
    if (tid < 160) {
      int r = tid / 10, c = tid % 10;
      float s = 0.f;
#pragma unroll 4
      for (int k = 0; k < 128; ++k) s = fmaf(h1s[r * 132 + k], gw[k * 10 + c], s);
      a.t2[((long)bz * 512 + i0 + r) * 10 + c] = s;
    }
  }
  __threadfence();
  grid.sync();

  // ================= P5: spat + readout + BCE ================================
  {
    float* t2s  = (float*)smem_u;                  // 5120
    float* wS   = (float*)(smem_u + 20480);        // 138
    float* osps = (float*)(smem_u + 21056);        // 16 x 12
    int ib = blk & 31, bz = blk >> 5;
    int i0 = ib * 16;
    for (int idx = tid; idx < 5120; idx += 512) t2s[idx] = a.t2[(long)bz * 5120 + idx];
    for (int idx = tid; idx < 138; idx += 512) wS[idx] = a.out_W[idx];
    __syncthreads();
    int r = tid >> 5, sk = tid & 31;
    const float* Arow = a.Abuf + (long)bz * 262144 + (long)(i0 + r) * 512;
    float acc[10] = {0, 0, 0, 0, 0, 0, 0, 0, 0, 0};
    for (int k = sk; k < 512; k += 32) {
      float av = Arow[k];
      const float* tp = &t2s[k * 10];
#pragma unroll
      for (int c = 0; c < 10; ++c) acc[c] = fmaf(av, tp[c], acc[c]);
    }
#pragma unroll
    for (int off = 16; off; off >>= 1)
#pragma unroll
      for (int c = 0; c < 10; ++c) acc[c] += __shfl_xor(acc[c], off);
    if (sk == 0) {
#pragma unroll
      for (int c = 0; c < 10; ++c) osps[r * 12 + c] = reluf_(acc[c] + a.gc2_b[c]);
    }
    __syncthreads();
    float l = 0.f;
    if (tid < 16) {
      int gid = bz * 512 + i0 + tid;
      float y = a.out_b[0];
#pragma unroll
      for (int k = 0; k < 10; ++k) y = fmaf(osps[tid * 12 + k], wS[k], y);
      const float* hp = &a.lhid[(long)gid * 128];
      for (int h = 0; h < 128; h += 4) {
        float4 hv = *(const float4*)&hp[h];
        y = fmaf(hv.x, wS[10 + h + 0], y);
        y = fmaf(hv.y, wS[10 + h + 1], y);
        y = fmaf(hv.z, wS[10 + h + 2], y);
        y = fmaf(hv.w, wS[10 + h + 3], y);
      }
      a.out[1 + gid] = sigmoidf_(y);
      l = fmaxf(y, 0.f) + log1pf(__expf(-fabsf(y))) - a.Y[gid] * y;
    }
    if (tid < 64) {
#pragma unroll
      for (int off = 8; off; off >>= 1) l += __shfl_down(l, off);
      if (tid == 0) atomicAdd(a.out, l * (1.0f / 4096.f));
    }
  }
}

// ---------------- launcher ----------------
extern "C" void kernel_launch(void* const* d_in, const int* in_sizes, int n_in,
                              void* d_out, int out_size, void* d_ws, size_t ws_size,
                              hipStream_t stream) {
  KArgs ka;
  ka.X       = (const float*)d_in[0];
  ka.Y       = (const float*)d_in[1];
  ka.adj     = (const float*)d_in[2];
  ka.V       = (const float*)d_in[3];
  ka.bv      = (const float*)d_in[4];
  ka.W1      = (const float*)d_in[5];
  ka.b1      = (const float*)d_in[6];
  ka.W2      = (const float*)d_in[7];
  ka.Wb      = (const float*)d_in[8];
  ka.wb      = (const float*)d_in[9];
  ka.conv_w  = (const float*)d_in[10];
  ka.conv_b  = (const float*)d_in[11];
  ka.convl_w = (const float*)d_in[12];
  ka.convl_b = (const float*)d_in[13];
  ka.gWih    = (const float*)d_in[14];
  ka.gWhh    = (const float*)d_in[15];
  ka.gbih    = (const float*)d_in[16];
  ka.gbhh    = (const float*)d_in[17];
  ka.gc1_W   = (const float*)d_in[18];
  ka.gc1_b   = (const float*)d_in[19];
  ka.gc2_W   = (const float*)d_in[20];
  ka.gc2_b   = (const float*)d_in[21];
  ka.out_W   = (const float*)d_in[22];
  ka.out_b   = (const float*)d_in[23];
  ka.Y2      = (const float*)d_in[1];
  ka.out = (float*)d_out;

  float* ws = (float*)d_ws;
  ka.lhid = ws; ws += 524288;
  ka.p1   = ws; ws += 262144;
  ka.p2   = ws; ws += 262144;
  ka.amx  = ws; ws += 2097152;
  ka.ssq  = ws; ws += 4096;
  ka.Abuf = ws; ws += 2097152;
  ka.t2   = ws; ws += 40960;
  float* Bpkf = ws; ws += 122880;
  float* WbTf = ws; ws += 262144;
  float* t1Tf = ws; ws += 524288;
  if (ws_size < (size_t)(ws - (float*)d_ws) * sizeof(float)) return;
  ka.Bpack  = (ushort_t*)Bpkf;
  ka.WbT_hi = (ushort_t*)WbTf;
  ka.WbT_lo = ka.WbT_hi + 262144;
  ka.t1T_hi = (ushort_t*)t1Tf;
  ka.t1T_lo = ka.t1T_hi + 524288;

  void* kargs[] = {(void*)&ka};
  hipLaunchCooperativeKernel((const void*)mega_kernel, dim3(256), dim3(512),
                             kargs, 0, stream);
}

// Round 9
// 263.140 us; speedup vs baseline: 2.5035x; 2.5035x over previous
//
#include <hip/hip_runtime.h>
#include <math.h>

// ---------------- sizes ----------------
#define Bn 8
#define Wn 20
#define Mn 512
#define Fn 16
#define Hn 128
#define HALFn 64
#define Kn 10

typedef __attribute__((ext_vector_type(8))) short short8;
typedef __attribute__((ext_vector_type(4))) float f32x4;
typedef unsigned short ushort_t;

__device__ __forceinline__ float sigmoidf_(float x) {
  return 1.0f / (1.0f + __expf(-x));
}
__device__ __forceinline__ float tanhf_(float x) {
  float xx = fminf(fmaxf(x, -15.f), 15.f);
  float e = __expf(2.f * xx);
  return (e - 1.f) / (e + 1.f);
}
__device__ __forceinline__ float reluf_(float x) { return fmaxf(x, 0.f); }
__device__ __forceinline__ float eluf_(float x) {
  return (x > 0.f) ? x : (__expf(x) - 1.f);
}
__device__ __forceinline__ ushort_t bf16_rne(float v) {
  unsigned u = __float_as_uint(v);
  u += 0x7FFFu + ((u >> 16) & 1u);
  return (ushort_t)(u >> 16);
}
__device__ __forceinline__ float bf16_to_f(ushort_t b) {
  return __uint_as_float(((unsigned)b) << 16);
}

// ---------------- prep: GRU weight pack + Wb transpose/split + zero init ----
__global__ __launch_bounds__(256) void pack_kernel(
    const float* __restrict__ Whh, const float* __restrict__ Wih,
    const float* __restrict__ Wb, ushort_t* __restrict__ Bpack,
    ushort_t* __restrict__ WbT_hi, ushort_t* __restrict__ WbT_lo,
    float* __restrict__ ssq, float* __restrict__ d_out) {
  int tid = threadIdx.x;
  if (blockIdx.x < 240) {
    int idx = blockIdx.x * 256 + tid;   // 24*5*512 = 61440
    if (idx < 4096) ssq[idx] = 0.f;
    if (idx == 0) d_out[0] = 0.f;
    if (idx >= 24 * 5 * 512) return;
    int j = idx & 7;
    int lane = (idx >> 3) & 63;
    int ks = (idx >> 9) % 5;
    int nt = idx / (5 * 512);
    int k = ks * 32 + (lane >> 4) * 8 + j;
    int g = (nt & 7) * 16 + (nt >> 3) * 128 + (lane & 15);
    float val = 0.f;
    if (k < 128) val = Whh[g * 128 + k];
    else if (k < 144) val = Wih[g * 16 + (k - 128)];
    ushort_t hb = bf16_rne(val);
    float lo = val - bf16_to_f(hb);
    Bpack[(((long)nt * 5 + ks) * 2 + 0) * 512 + lane * 8 + j] = hb;
    Bpack[(((long)nt * 5 + ks) * 2 + 1) * 512 + lane * 8 + j] = bf16_rne(lo);
  } else {
    int t = blockIdx.x - 240;           // 0..63
    int k0 = (t >> 3) * 64, j0 = (t & 7) * 64;
    __shared__ float wt[64][65];
    for (int idx = tid; idx < 4096; idx += 256) {
      int r = idx >> 6, c = idx & 63;
      wt[r][c] = Wb[(long)(k0 + r) * 512 + j0 + c];
    }
    __syncthreads();
    for (int idx = tid; idx < 4096; idx += 256) {
      int r = idx >> 6, c = idx & 63;
      float v = wt[c][r];
      ushort_t hb = bf16_rne(v);
      WbT_hi[(long)(j0 + r) * 512 + k0 + c] = hb;
      WbT_lo[(long)(j0 + r) * 512 + k0 + c] = bf16_rne(v - bf16_to_f(hb));
    }
  }
}

// ---------------- GRU: split-bf16 MFMA, double-buffered h (1 barrier/step),
// 7 independent MFMA chains; fused p1/p2 epilogue.
// __launch_bounds__(512,1): 256-VGPR budget so the 104-VGPR persistent weight
// fragments are truly register-resident (at (512,2)/128 the compiler re-fetched
// them from L2 every step — VGPR_Count was 96 < 104 needed).
#define LDK 168
#define HSZ (16 * LDK)
__global__ __launch_bounds__(512, 1) void gru_kernel(
    const float* __restrict__ X, const ushort_t* __restrict__ Bpack,
    const float* __restrict__ bih, const float* __restrict__ bhh,
    const float* __restrict__ W1, const float* __restrict__ W2,
    const float* __restrict__ b1, float* __restrict__ last_hid,
    float* __restrict__ p1, float* __restrict__ p2) {
  const int tid = threadIdx.x;
  const int wave = tid >> 6;
  const int lane = tid & 63;
  const int quad = lane >> 4;
  const int jl = lane & 15;
  const int j0 = wave * 16;
  const int blk = blockIdx.x;
  const int b = blk >> 5;
  const int m0 = (blk & 31) * 16;

  __shared__ __align__(16) ushort_t smem_hs[4 * HSZ];  // hi0,hi1,lo0,lo1

  short8 frR[5][2], frZ[5][2], frN[4][2], frXN[2];
#pragma unroll
  for (int ks = 0; ks < 5; ++ks) {
#pragma unroll
    for (int p = 0; p < 2; ++p) {
      frR[ks][p] = *(const short8*)&Bpack[(((long)(wave) * 5 + ks) * 2 + p) * 512 + lane * 8];
      frZ[ks][p] = *(const short8*)&Bpack[(((long)(8 + wave) * 5 + ks) * 2 + p) * 512 + lane * 8];
    }
  }
#pragma unroll
  for (int ks = 0; ks < 4; ++ks) {
#pragma unroll
    for (int p = 0; p < 2; ++p)
      frN[ks][p] = *(const short8*)&Bpack[(((long)(16 + wave) * 5 + ks) * 2 + p) * 512 + lane * 8];
  }
#pragma unroll
  for (int p = 0; p < 2; ++p)
    frXN[p] = *(const short8*)&Bpack[(((long)(16 + wave) * 5 + 4) * 2 + p) * 512 + lane * 8];

  const float cr  = bih[j0 + jl] + bhh[j0 + jl];
  const float cz  = bih[128 + j0 + jl] + bhh[128 + j0 + jl];
  const float cnx = bih[256 + j0 + jl];
  const float cnh = bhh[256 + j0 + jl];

  for (int i = tid; i < 4 * HSZ; i += 512) smem_hs[i] = 0;

  const float* Xb = X + (long)b * (Wn * Mn * Fn) + (long)m0 * Fn;
  float x0 = 0.f;
  if (tid < 256) x0 = Xb[tid];
  __syncthreads();
  if (tid < 256) {
    int s = tid >> 4, f = tid & 15;
    ushort_t hb = bf16_rne(x0);
    smem_hs[0 * HSZ + s * LDK + 128 + f] = hb;
    smem_hs[2 * HSZ + s * LDK + 128 + f] = bf16_rne(x0 - bf16_to_f(hb));
  }
  __syncthreads();

  float hp[4] = {0.f, 0.f, 0.f, 0.f};

  for (int t = 0; t < Wn; ++t) {
    const int cur = t & 1, nxt = cur ^ 1;
    const int hiC = cur * HSZ, loC = (2 + cur) * HSZ;
    const int hiN = nxt * HSZ, loN = (2 + nxt) * HSZ;
    float xpre = 0.f;
    if (tid < 256 && t < Wn - 1) xpre = Xb[(long)(t + 1) * (Mn * Fn) + tid];

    // 7 independent MFMA chains (split by ks parity) — max depth 9
    f32x4 aR[2], aZ[2], aHN[2], aXN;
    aR[0] = aR[1] = aZ[0] = aZ[1] = aHN[0] = aHN[1] = aXN = (f32x4){0.f, 0.f, 0.f, 0.f};
#pragma unroll
    for (int ks = 0; ks < 5; ++ks) {
      const int p = ks & 1;
      short8 ah = *(const short8*)&smem_hs[hiC + jl * LDK + ks * 32 + quad * 8];
      short8 al = *(const short8*)&smem_hs[loC + jl * LDK + ks * 32 + quad * 8];
      aR[p] = __builtin_amdgcn_mfma_f32_16x16x32_bf16(ah, frR[ks][0], aR[p], 0, 0, 0);
      aR[p] = __builtin_amdgcn_mfma_f32_16x16x32_bf16(ah, frR[ks][1], aR[p], 0, 0, 0);
      aR[p] = __builtin_amdgcn_mfma_f32_16x16x32_bf16(al, frR[ks][0], aR[p], 0, 0, 0);
      aZ[p] = __builtin_amdgcn_mfma_f32_16x16x32_bf16(ah, frZ[ks][0], aZ[p], 0, 0, 0);
      aZ[p] = __builtin_amdgcn_mfma_f32_16x16x32_bf16(ah, frZ[ks][1], aZ[p], 0, 0, 0);
      aZ[p] = __builtin_amdgcn_mfma_f32_16x16x32_bf16(al, frZ[ks][0], aZ[p], 0, 0, 0);
      if (ks < 4) {
        aHN[p] = __builtin_amdgcn_mfma_f32_16x16x32_bf16(ah, frN[ks][0], aHN[p], 0, 0, 0);
        aHN[p] = __builtin_amdgcn_mfma_f32_16x16x32_bf16(ah, frN[ks][1], aHN[p], 0, 0, 0);
        aHN[p] = __builtin_amdgcn_mfma_f32_16x16x32_bf16(al, frN[ks][0], aHN[p], 0, 0, 0);
      } else {
        aXN = __builtin_amdgcn_mfma_f32_16x16x32_bf16(ah, frXN[0], aXN, 0, 0, 0);
        aXN = __builtin_amdgcn_mfma_f32_16x16x32_bf16(ah, frXN[1], aXN, 0, 0, 0);
        aXN = __builtin_amdgcn_mfma_f32_16x16x32_bf16(al, frXN[0], aXN, 0, 0, 0);
      }
    }

    // gate math; write h(t+1) into the NEXT buffer (no read/write conflict)
#pragma unroll
    for (int reg = 0; reg < 4; ++reg) {
      float r = sigmoidf_(aR[0][reg] + aR[1][reg] + cr);
      float z = sigmoidf_(aZ[0][reg] + aZ[1][reg] + cz);
      float n = tanhf_(aXN[reg] + cnx + r * (aHN[0][reg] + aHN[1][reg] + cnh));
      float h = (1.f - z) * n + z * hp[reg];
      hp[reg] = h;
      int s = quad * 4 + reg;
      ushort_t hb = bf16_rne(h);
      smem_hs[hiN + s * LDK + j0 + jl] = hb;
      smem_hs[loN + s * LDK + j0 + jl] = bf16_rne(h - bf16_to_f(hb));
    }
    if (tid < 256 && t < Wn - 1) {
      int s = tid >> 4, f = tid & 15;
      ushort_t hb = bf16_rne(xpre);
      smem_hs[hiN + s * LDK + 128 + f] = hb;
      smem_hs[loN + s * LDK + 128 + f] = bf16_rne(xpre - bf16_to_f(hb));
    }
    __syncthreads();   // single barrier per step
  }

  float* hs_f = (float*)smem_hs;          // 16 x 132 floats
#pragma unroll
  for (int reg = 0; reg < 4; ++reg) {
    int s = quad * 4 + reg;
    float h = hp[reg];
    last_hid[(long)(blk * 16 + s) * Hn + j0 + jl] = h;
    hs_f[s * 132 + j0 + jl] = h;
  }
  __syncthreads();
  {
    int k = tid & 63;
    int part = (tid >> 6) & 1;
    int sg = tid >> 7;
    const float* Wp = part ? W2 : W1;
    float a[4];
    float init = part ? 0.f : b1[k];
    a[0] = a[1] = a[2] = a[3] = init;
    for (int h = 0; h < 128; h += 4) {
      float4 w = *(const float4*)&Wp[k * 128 + h];
#pragma unroll
      for (int rr = 0; rr < 4; ++rr) {
        float4 q = *(const float4*)&hs_f[(sg * 4 + rr) * 132 + h];
        a[rr] += q.x * w.x + q.y * w.y + q.z * w.z + q.w * w.w;
      }
    }
    float* outp = part ? p2 : p1;
#pragma unroll
    for (int rr = 0; rr < 4; ++rr)
      outp[(long)(blk * 16 + sg * 4 + rr) * 64 + k] = a[rr];
  }
}

// ---------------- fused conv + t1; t1 emitted as bf16 hi/lo TRANSPOSED [h][m] ----
__global__ __launch_bounds__(128) void conv_t1_kernel(
    const float* __restrict__ X, const float* __restrict__ conv_w,
    const float* __restrict__ conv_b, const float* __restrict__ convl_w,
    const float* __restrict__ convl_b, const float* __restrict__ gc1_W,
    ushort_t* __restrict__ t1T_hi, ushort_t* __restrict__ t1T_lo) {
  int tid = threadIdx.x;
  int n0 = blockIdx.x * 8;
  int b = n0 >> 9, m0 = n0 & 511;
  __shared__ float xs[8][16][20];
  __shared__ float cw[3200];
  __shared__ float clw[1600];
  __shared__ float rs[8][32];
  for (int idx = tid; idx < 3200; idx += 128) cw[idx] = conv_w[idx];
  for (int idx = tid; idx < 1600; idx += 128) clw[idx] = convl_w[idx];
  for (int w = 0; w < 20; ++w)
    xs[tid >> 4][tid & 15][w] = X[((long)(b * 20 + w) * 512 + m0) * 16 + tid];
  __syncthreads();
  if (tid < 80) {
    int s = tid / 10, k = tid % 10;
    float a0 = conv_b[k];
    float l0 = convl_b[k], l1 = convl_b[k];
    for (int f = 0; f < 16; ++f) {
#pragma unroll
      for (int w = 0; w < 20; ++w) a0 = fmaf(xs[s][f][w], cw[k * 320 + f * 20 + w], a0);
#pragma unroll
      for (int q = 0; q < 10; ++q) {
        float wv = clw[k * 160 + f * 10 + q];
        l0 = fmaf(xs[s][f][2 * q], wv, l0);
        l1 = fmaf(xs[s][f][2 * q + 1], wv, l1);
      }
    }
    rs[s][k * 3 + 0] = reluf_(a0);
    rs[s][k * 3 + 1] = reluf_(l0);
    rs[s][k * 3 + 2] = reluf_(l1);
  }
  __syncthreads();
  float w[30];
#pragma unroll
  for (int q = 0; q < 30; ++q) w[q] = gc1_W[q * 128 + tid];
  long base = ((long)b * 128 + tid) * 512 + m0;
#pragma unroll
  for (int s = 0; s < 8; ++s) {
    float a = 0.f;
#pragma unroll
    for (int q = 0; q < 30; ++q) a = fmaf(rs[s][q], w[q], a);
    ushort_t hb = bf16_rne(a);
    t1T_hi[base + s] = hb;
    t1T_lo[base + s] = bf16_rne(a - bf16_to_f(hb));
  }
}

// ---------------- a_mx raw (32x32 tile) + fused column sum-of-squares ----------------
__global__ __launch_bounds__(256) void amx_kernel(
    const float* __restrict__ p1, const float* __restrict__ p2,
    const float* __restrict__ V, const float* __restrict__ bv,
    float* __restrict__ amx, float* __restrict__ ssq) {
  int tid = threadIdx.x;
  int j0 = blockIdx.x * 32, i0 = blockIdx.y * 32, bz = blockIdx.z;
  __shared__ float p1s[32][68];
  __shared__ float p2s[32][68];
  __shared__ float Vs[64];
  __shared__ float cred[16][33];
  if (tid < 64) Vs[tid] = V[tid];
  {
    int rr = tid >> 3, c0 = (tid & 7) * 8;
    *(float4*)&p1s[rr][c0]     = *(const float4*)&p1[(long)(bz * 512 + j0 + rr) * 64 + c0];
    *(float4*)&p1s[rr][c0 + 4] = *(const float4*)&p1[(long)(bz * 512 + j0 + rr) * 64 + c0 + 4];
    *(float4*)&p2s[rr][c0]     = *(const float4*)&p2[(long)(bz * 512 + i0 + rr) * 64 + c0];
    *(float4*)&p2s[rr][c0 + 4] = *(const float4*)&p2[(long)(bz * 512 + i0 + rr) * 64 + c0 + 4];
  }
  __syncthreads();
  int r0 = tid >> 4, c0 = tid & 15;
  float acc[2][2] = {{0.f, 0.f}, {0.f, 0.f}};
  for (int k = 0; k < 64; ++k) {
    float vj0 = p1s[c0][k], vj1 = p1s[c0 + 16][k];
    float vi0 = p2s[r0][k], vi1 = p2s[r0 + 16][k];
    float vk = Vs[k];
    acc[0][0] = fmaf(eluf_(vj0 + vi0), vk, acc[0][0]);
    acc[0][1] = fmaf(eluf_(vj1 + vi0), vk, acc[0][1]);
    acc[1][0] = fmaf(eluf_(vj0 + vi1), vk, acc[1][0]);
    acc[1][1] = fmaf(eluf_(vj1 + vi1), vk, acc[1][1]);
  }
  float bvv = bv[0];
  float s2[2] = {0.f, 0.f};
#pragma unroll
  for (int a = 0; a < 2; ++a)
#pragma unroll
    for (int c = 0; c < 2; ++c) {
      float v = acc[a][c] + bvv;
      amx[((long)(bz * 512 + i0 + r0 + a * 16)) * 512 + j0 + c0 + c * 16] = v;
      s2[c] += v * v;
    }
  cred[r0][c0] = s2[0];
  cred[r0][c0 + 16] = s2[1];
  __syncthreads();
  if (tid < 32) {
    float s = 0.f;
#pragma unroll
    for (int p = 0; p < 16; ++p) s += cred[p][tid];
    atomicAdd(&ssq[bz * 512 + j0 + tid], s);
  }
}

// ---- gemm_cA via split-bf16 MFMA ----
#define CPK 40
__global__ __launch_bounds__(128, 2) void gemm_cA(
    const float* __restrict__ amx, const ushort_t* __restrict__ WbT_hi,
    const ushort_t* __restrict__ WbT_lo, const float* __restrict__ adj,
    const float* __restrict__ wb, const float* __restrict__ ssq,
    float* __restrict__ A) {
  const int bz = blockIdx.z;
  const int i0 = blockIdx.y * 128;
  const int j0 = blockIdx.x * 64;
  const int tid = threadIdx.x;
  const int wave = tid >> 6;
  const int lane = tid & 63;
  const int quad = lane >> 4, jl = lane & 15;

  __shared__ __align__(16) ushort_t Ahi[128][CPK];
  __shared__ __align__(16) ushort_t Alo[128][CPK];
  __shared__ __align__(16) ushort_t Bhi[64][CPK];
  __shared__ __align__(16) ushort_t Blo[64][CPK];
  __shared__ float rs_s[512];

  const float* Abase = amx + (long)bz * 262144;
  const float* sb = ssq + bz * 512;
  for (int i = tid; i < 512; i += 128)
    rs_s[i] = 1.f / fmaxf(sqrtf(sb[i]), 1e-12f);

  f32x4 acc[4][4];
#pragma unroll
  for (int a = 0; a < 4; ++a)
#pragma unroll
    for (int c = 0; c < 4; ++c) acc[a][c] = (f32x4){0.f, 0.f, 0.f, 0.f};

  for (int kk0 = 0; kk0 < 512; kk0 += 32) {
    __syncthreads();
#pragma unroll
    for (int l = 0; l < 8; ++l) {
      int e = l * 512 + tid * 4;
      int r = e >> 5, kq = e & 31;
      float4 v = *(const float4*)&Abase[(long)(i0 + r) * 512 + kk0 + kq];
      float4 sc = *(const float4*)&rs_s[kk0 + kq];
      float vv[4] = {v.x * sc.x, v.y * sc.y, v.z * sc.z, v.w * sc.w};
#pragma unroll
      for (int q = 0; q < 4; ++q) {
        ushort_t hb = bf16_rne(vv[q]);
        Ahi[r][kq + q] = hb;
        Alo[r][kq + q] = bf16_rne(vv[q] - bf16_to_f(hb));
      }
    }
#pragma unroll
    for (int l = 0; l < 2; ++l) {
      int e = l * 1024 + tid * 8;
      int r = e >> 5, kc = e & 31;
      *(uint4*)&Bhi[r][kc] = *(const uint4*)&WbT_hi[(long)(j0 + r) * 512 + kk0 + kc];
      *(uint4*)&Blo[r][kc] = *(const uint4*)&WbT_lo[(long)(j0 + r) * 512 + kk0 + kc];
    }
    __syncthreads();
    short8 ah[4], al[4], bh[4], bl[4];
#pragma unroll
    for (int tm = 0; tm < 4; ++tm) {
      ah[tm] = *(const short8*)&Ahi[wave * 64 + tm * 16 + jl][quad * 8];
      al[tm] = *(const short8*)&Alo[wave * 64 + tm * 16 + jl][quad * 8];
    }
#pragma unroll
    for (int tn = 0; tn < 4; ++tn) {
      bh[tn] = *(const short8*)&Bhi[tn * 16 + jl][quad * 8];
      bl[tn] = *(const short8*)&Blo[tn * 16 + jl][quad * 8];
    }
#pragma unroll
    for (int tm = 0; tm < 4; ++tm)
#pragma unroll
      for (int tn = 0; tn < 4; ++tn) {
        acc[tm][tn] = __builtin_amdgcn_mfma_f32_16x16x32_bf16(ah[tm], bh[tn], acc[tm][tn], 0, 0, 0);
        acc[tm][tn] = __builtin_amdgcn_mfma_f32_16x16x32_bf16(ah[tm], bl[tn], acc[tm][tn], 0, 0, 0);
        acc[tm][tn] = __builtin_amdgcn_mfma_f32_16x16x32_bf16(al[tm], bh[tn], acc[tm][tn], 0, 0, 0);
      }
  }

  const float wbv = wb[0];
#pragma unroll
  for (int tn = 0; tn < 4; ++tn) {
    int j = j0 + tn * 16 + jl;
    float sj = rs_s[j];
#pragma unroll
    for (int tm = 0; tm < 4; ++tm) {
#pragma unroll
      for (int reg = 0; reg < 4; ++reg) {
        int i = i0 + wave * 64 + tm * 16 + quad * 4 + reg;
        long ofs = (long)bz * 262144 + (long)i * 512 + j;
        float c = sigmoidf_(acc[tm][tn][reg] + wbv);
        float am = Abase[(long)i * 512 + j] * sj;
        float ad = adj[(long)i * 512 + j];
        A[ofs] = ad * c + am * (1.f - c);
      }
    }
  }
}

// ---------------- gemm_h1 (BM=16, 256 blocks) + fused t2 = h1 @ gc2_W ----------------
__global__ __launch_bounds__(256, 2) void gemm_h1t2(
    const float* __restrict__ A, const ushort_t* __restrict__ t1T_hi,
    const ushort_t* __restrict__ t1T_lo, const float* __restrict__ gc1_b,
    const float* __restrict__ gc2_W, float* __restrict__ t2) {
  const int bz = blockIdx.y;
  const int i0 = blockIdx.x * 16;
  const int tid = threadIdx.x;
  const int wave = tid >> 6;
  const int lane = tid & 63;
  const int quad = lane >> 4, jl = lane & 15;

  __shared__ __align__(16) ushort_t Ahi[16][CPK];
  __shared__ __align__(16) ushort_t Alo[16][CPK];
  __shared__ __align__(16) ushort_t Bhi[128][CPK];
  __shared__ __align__(16) ushort_t Blo[128][CPK];
  __shared__ float h1s[16][132];
  __shared__ float gw[1280];

  const float* Ab = A + (long)bz * 262144;
  for (int idx = tid; idx < 1280; idx += 256) gw[idx] = gc2_W[idx];

  f32x4 acc[2];
  acc[0] = acc[1] = (f32x4){0.f, 0.f, 0.f, 0.f};

  for (int kk0 = 0; kk0 < 512; kk0 += 32) {
    __syncthreads();
    {
      int e = tid * 2;
      int r = e >> 5, kq = e & 31;
      float2 v = *(const float2*)&Ab[(long)(i0 + r) * 512 + kk0 + kq];
      ushort_t hb0 = bf16_rne(v.x);
      Ahi[r][kq] = hb0;
      Alo[r][kq] = bf16_rne(v.x - bf16_to_f(hb0));
      ushort_t hb1 = bf16_rne(v.y);
      Ahi[r][kq + 1] = hb1;
      Alo[r][kq + 1] = bf16_rne(v.y - bf16_to_f(hb1));
    }
#pragma unroll
    for (int l = 0; l < 2; ++l) {
      int e = l * 2048 + tid * 8;
      int r = e >> 5, kc = e & 31;
      *(uint4*)&Bhi[r][kc] = *(const uint4*)&t1T_hi[((long)bz * 128 + r) * 512 + kk0 + kc];
      *(uint4*)&Blo[r][kc] = *(const uint4*)&t1T_lo[((long)bz * 128 + r) * 512 + kk0 + kc];
    }
    __syncthreads();
    short8 ah = *(const short8*)&Ahi[jl][quad * 8];
    short8 al = *(const short8*)&Alo[jl][quad * 8];
    short8 bh[2], bl[2];
#pragma unroll
    for (int tn = 0; tn < 2; ++tn) {
      bh[tn] = *(const short8*)&Bhi[wave * 32 + tn * 16 + jl][quad * 8];
      bl[tn] = *(const short8*)&Blo[wave * 32 + tn * 16 + jl][quad * 8];
    }
#pragma unroll
    for (int tn = 0; tn < 2; ++tn) {
      acc[tn] = __builtin_amdgcn_mfma_f32_16x16x32_bf16(ah, bh[tn], acc[tn], 0, 0, 0);
      acc[tn] = __builtin_amdgcn_mfma_f32_16x16x32_bf16(ah, bl[tn], acc[tn], 0, 0, 0);
      acc[tn] = __builtin_amdgcn_mfma_f32_16x16x32_bf16(al, bh[tn], acc[tn], 0, 0, 0);
    }
  }
  __syncthreads();
#pragma unroll
  for (int tn = 0; tn < 2; ++tn) {
    int n = wave * 32 + tn * 16 + jl;
    float bb = gc1_b[n];
#pragma unroll
    for (int reg = 0; reg < 4; ++reg) {
      int r = quad * 4 + reg;
      h1s[r][n] = reluf_(acc[tn][reg] + bb);
    }
  }
  __syncthreads();
  if (tid < 160) {
    int r = tid / 10, c = tid % 10;
    float a = 0.f;
#pragma unroll 4
    for (int k = 0; k < 128; ++k) a = fmaf(h1s[r][k], gw[k * 10 + c], a);
    t2[((long)bz * 512 + i0 + r) * 10 + c] = a;
  }
}

// ---------------- out_spatial = relu(A @ t2 + b2) fused with readout + BCE ----------
__global__ __launch_bounds__(256) void spat_readout(
    const float* __restrict__ A, const float* __restrict__ t2,
    const float* __restrict__ gc2_b, const float* __restrict__ last_hid,
    const float* __restrict__ out_W, const float* __restrict__ out_b,
    const float* __restrict__ Y, float* __restrict__ d_out) {
  int tid = threadIdx.x;
  int bz = blockIdx.y;
  int i0 = blockIdx.x * 16;
  __shared__ float t2s[5120];
  __shared__ float wS[138];
  __shared__ float osps[16][12];
  for (int idx = tid; idx < 5120; idx += 256) t2s[idx] = t2[(long)bz * 5120 + idx];
  for (int idx = tid; idx < 138; idx += 256) wS[idx] = out_W[idx];
  __syncthreads();
  int r = tid >> 4, sk = tid & 15;
  const float* Arow = A + (long)bz * 262144 + (long)(i0 + r) * 512;
  float acc[10] = {0, 0, 0, 0, 0, 0, 0, 0, 0, 0};
  for (int k = sk; k < 512; k += 16) {
    float av = Arow[k];
    const float* tp = &t2s[k * 10];
#pragma unroll
    for (int c = 0; c < 10; ++c) acc[c] = fmaf(av, tp[c], acc[c]);
  }
#pragma unroll
  for (int off = 8; off; off >>= 1)
#pragma unroll
    for (int c = 0; c < 10; ++c) acc[c] += __shfl_xor(acc[c], off);
  if (sk == 0) {
#pragma unroll
    for (int c = 0; c < 10; ++c) osps[r][c] = reluf_(acc[c] + gc2_b[c]);
  }
  __syncthreads();
  float l = 0.f;
  if (tid < 16) {
    int gid = bz * 512 + i0 + tid;
    float y = out_b[0];
#pragma unroll
    for (int k = 0; k < 10; ++k) y = fmaf(osps[tid][k], wS[k], y);
    const float* hp = &last_hid[(long)gid * 128];
    for (int h = 0; h < 128; h += 4) {
      float4 hv = *(const float4*)&hp[h];
      y = fmaf(hv.x, wS[10 + h + 0], y);
      y = fmaf(hv.y, wS[10 + h + 1], y);
      y = fmaf(hv.z, wS[10 + h + 2], y);
      y = fmaf(hv.w, wS[10 + h + 3], y);
    }
    d_out[1 + gid] = sigmoidf_(y);
    l = fmaxf(y, 0.f) + log1pf(__expf(-fabsf(y))) - Y[gid] * y;
  }
  if (tid < 64) {
#pragma unroll
    for (int off = 8; off; off >>= 1) l += __shfl_down(l, off);
    if (tid == 0) atomicAdd(d_out, l * (1.0f / 4096.f));
  }
}

// ---------------- launcher ----------------
extern "C" void kernel_launch(void* const* d_in, const int* in_sizes, int n_in,
                              void* d_out, int out_size, void* d_ws, size_t ws_size,
                              hipStream_t stream) {
  const float* X       = (const float*)d_in[0];
  const float* Y       = (const float*)d_in[1];
  const float* adj     = (const float*)d_in[2];
  const float* V       = (const float*)d_in[3];
  const float* bv      = (const float*)d_in[4];
  const float* W1      = (const float*)d_in[5];
  const float* b1      = (const float*)d_in[6];
  const float* W2      = (const float*)d_in[7];
  const float* Wb      = (const float*)d_in[8];
  const float* wb      = (const float*)d_in[9];
  const float* conv_w  = (const float*)d_in[10];
  const float* conv_b  = (const float*)d_in[11];
  const float* convl_w = (const float*)d_in[12];
  const float* convl_b = (const float*)d_in[13];
  const float* gWih    = (const float*)d_in[14];
  const float* gWhh    = (const float*)d_in[15];
  const float* gbih    = (const float*)d_in[16];
  const float* gbhh    = (const float*)d_in[17];
  const float* gc1_W   = (const float*)d_in[18];
  const float* gc1_b   = (const float*)d_in[19];
  const float* gc2_W   = (const float*)d_in[20];
  const float* gc2_b   = (const float*)d_in[21];
  const float* out_W   = (const float*)d_in[22];
  const float* out_b   = (const float*)d_in[23];
  float* out = (float*)d_out;

  float* ws = (float*)d_ws;
  float* lhid  = ws; ws += 524288;
  float* p1    = ws; ws += 262144;
  float* p2    = ws; ws += 262144;
  float* amx   = ws; ws += 2097152;
  float* ssq   = ws; ws += 4096;
  float* Abuf  = ws; ws += 2097152;
  float* t2    = ws; ws += 40960;
  float* Bpkf  = ws; ws += 122880;   // 245760 ushorts (GRU pack)
  float* WbTf  = ws; ws += 262144;   // 2 x 262144 ushorts
  float* t1Tf  = ws; ws += 524288;   // 2 x 524288 ushorts
  if (ws_size < (size_t)(ws - (float*)d_ws) * sizeof(float)) return;
  ushort_t* Bpack  = (ushort_t*)Bpkf;
  ushort_t* WbT_hi = (ushort_t*)WbTf;
  ushort_t* WbT_lo = WbT_hi + 262144;
  ushort_t* t1T_hi = (ushort_t*)t1Tf;
  ushort_t* t1T_lo = t1T_hi + 524288;

  pack_kernel<<<304, 256, 0, stream>>>(gWhh, gWih, Wb, Bpack, WbT_hi, WbT_lo,
                                       ssq, out);
  gru_kernel<<<256, 512, 0, stream>>>(X, Bpack, gbih, gbhh, W1, W2, b1,
                                      lhid, p1, p2);
  conv_t1_kernel<<<512, 128, 0, stream>>>(X, conv_w, conv_b, convl_w, convl_b,
                                          gc1_W, t1T_hi, t1T_lo);
  amx_kernel<<<dim3(16, 16, 8), 256, 0, stream>>>(p1, p2, V, bv, amx, ssq);
  gemm_cA<<<dim3(8, 4, 8), 128, 0, stream>>>(amx, WbT_hi, WbT_lo, adj, wb,
                                             ssq, Abuf);
  gemm_h1t2<<<dim3(32, 8), 256, 0, stream>>>(Abuf, t1T_hi, t1T_lo, gc1_b,
                                             gc2_W, t2);
  spat_readout<<<dim3(32, 8), 256, 0, stream>>>(Abuf, t2, gc2_b, lhid,
                                                out_W, out_b, Y, out);
}

// Round 10
// 256.083 us; speedup vs baseline: 2.5725x; 1.0276x over previous
//
#include <hip/hip_runtime.h>
#include <math.h>

// ---------------- sizes ----------------
#define Bn 8
#define Wn 20
#define Mn 512
#define Fn 16
#define Hn 128
#define HALFn 64
#define Kn 10

typedef __attribute__((ext_vector_type(8))) short short8;
typedef __attribute__((ext_vector_type(4))) float f32x4;
typedef unsigned short ushort_t;

__device__ __forceinline__ float sigmoidf_(float x) {
  return 1.0f / (1.0f + __expf(-x));
}
__device__ __forceinline__ float tanhf_(float x) {
  float xx = fminf(fmaxf(x, -15.f), 15.f);
  float e = __expf(2.f * xx);
  return (e - 1.f) / (e + 1.f);
}
__device__ __forceinline__ float reluf_(float x) { return fmaxf(x, 0.f); }
__device__ __forceinline__ float eluf_(float x) {
  return (x > 0.f) ? x : (__expf(x) - 1.f);
}
__device__ __forceinline__ ushort_t bf16_rne(float v) {
  unsigned u = __float_as_uint(v);
  u += 0x7FFFu + ((u >> 16) & 1u);
  return (ushort_t)(u >> 16);
}
__device__ __forceinline__ float bf16_to_f(ushort_t b) {
  return __uint_as_float(((unsigned)b) << 16);
}

// ---------------- prep: GRU weight pack + Wb transpose/split + zero init ----
__global__ __launch_bounds__(256) void pack_kernel(
    const float* __restrict__ Whh, const float* __restrict__ Wih,
    const float* __restrict__ Wb, ushort_t* __restrict__ Bpack,
    ushort_t* __restrict__ WbT_hi, ushort_t* __restrict__ WbT_lo,
    float* __restrict__ ssq, float* __restrict__ d_out) {
  int tid = threadIdx.x;
  if (blockIdx.x < 240) {
    int idx = blockIdx.x * 256 + tid;   // 24*5*512 = 61440
    if (idx < 4096) ssq[idx] = 0.f;
    if (idx == 0) d_out[0] = 0.f;
    if (idx >= 24 * 5 * 512) return;
    int j = idx & 7;
    int lane = (idx >> 3) & 63;
    int ks = (idx >> 9) % 5;
    int nt = idx / (5 * 512);
    int k = ks * 32 + (lane >> 4) * 8 + j;
    int g = (nt & 7) * 16 + (nt >> 3) * 128 + (lane & 15);
    float val = 0.f;
    if (k < 128) val = Whh[g * 128 + k];
    else if (k < 144) val = Wih[g * 16 + (k - 128)];
    ushort_t hb = bf16_rne(val);
    float lo = val - bf16_to_f(hb);
    Bpack[(((long)nt * 5 + ks) * 2 + 0) * 512 + lane * 8 + j] = hb;
    Bpack[(((long)nt * 5 + ks) * 2 + 1) * 512 + lane * 8 + j] = bf16_rne(lo);
  } else {
    int t = blockIdx.x - 240;           // 0..63
    int k0 = (t >> 3) * 64, j0 = (t & 7) * 64;
    __shared__ float wt[64][65];
    for (int idx = tid; idx < 4096; idx += 256) {
      int r = idx >> 6, c = idx & 63;
      wt[r][c] = Wb[(long)(k0 + r) * 512 + j0 + c];
    }
    __syncthreads();
    for (int idx = tid; idx < 4096; idx += 256) {
      int r = idx >> 6, c = idx & 63;
      float v = wt[c][r];
      ushort_t hb = bf16_rne(v);
      WbT_hi[(long)(j0 + r) * 512 + k0 + c] = hb;
      WbT_lo[(long)(j0 + r) * 512 + k0 + c] = bf16_rne(v - bf16_to_f(hb));
    }
  }
}

// ---------------- GRU (unchanged from round 9; pinned ~54 us) ----------------
#define LDK 168
#define HSZ (16 * LDK)
__global__ __launch_bounds__(512, 1) void gru_kernel(
    const float* __restrict__ X, const ushort_t* __restrict__ Bpack,
    const float* __restrict__ bih, const float* __restrict__ bhh,
    const float* __restrict__ W1, const float* __restrict__ W2,
    const float* __restrict__ b1, float* __restrict__ last_hid,
    float* __restrict__ p1, float* __restrict__ p2) {
  const int tid = threadIdx.x;
  const int wave = tid >> 6;
  const int lane = tid & 63;
  const int quad = lane >> 4;
  const int jl = lane & 15;
  const int j0 = wave * 16;
  const int blk = blockIdx.x;
  const int b = blk >> 5;
  const int m0 = (blk & 31) * 16;

  __shared__ __align__(16) ushort_t smem_hs[4 * HSZ];  // hi0,hi1,lo0,lo1

  short8 frR[5][2], frZ[5][2], frN[4][2], frXN[2];
#pragma unroll
  for (int ks = 0; ks < 5; ++ks) {
#pragma unroll
    for (int p = 0; p < 2; ++p) {
      frR[ks][p] = *(const short8*)&Bpack[(((long)(wave) * 5 + ks) * 2 + p) * 512 + lane * 8];
      frZ[ks][p] = *(const short8*)&Bpack[(((long)(8 + wave) * 5 + ks) * 2 + p) * 512 + lane * 8];
    }
  }
#pragma unroll
  for (int ks = 0; ks < 4; ++ks) {
#pragma unroll
    for (int p = 0; p < 2; ++p)
      frN[ks][p] = *(const short8*)&Bpack[(((long)(16 + wave) * 5 + ks) * 2 + p) * 512 + lane * 8];
  }
#pragma unroll
  for (int p = 0; p < 2; ++p)
    frXN[p] = *(const short8*)&Bpack[(((long)(16 + wave) * 5 + 4) * 2 + p) * 512 + lane * 8];

  const float cr  = bih[j0 + jl] + bhh[j0 + jl];
  const float cz  = bih[128 + j0 + jl] + bhh[128 + j0 + jl];
  const float cnx = bih[256 + j0 + jl];
  const float cnh = bhh[256 + j0 + jl];

  for (int i = tid; i < 4 * HSZ; i += 512) smem_hs[i] = 0;

  const float* Xb = X + (long)b * (Wn * Mn * Fn) + (long)m0 * Fn;
  float x0 = 0.f;
  if (tid < 256) x0 = Xb[tid];
  __syncthreads();
  if (tid < 256) {
    int s = tid >> 4, f = tid & 15;
    ushort_t hb = bf16_rne(x0);
    smem_hs[0 * HSZ + s * LDK + 128 + f] = hb;
    smem_hs[2 * HSZ + s * LDK + 128 + f] = bf16_rne(x0 - bf16_to_f(hb));
  }
  __syncthreads();

  float hp[4] = {0.f, 0.f, 0.f, 0.f};

  for (int t = 0; t < Wn; ++t) {
    const int cur = t & 1, nxt = cur ^ 1;
    const int hiC = cur * HSZ, loC = (2 + cur) * HSZ;
    const int hiN = nxt * HSZ, loN = (2 + nxt) * HSZ;
    float xpre = 0.f;
    if (tid < 256 && t < Wn - 1) xpre = Xb[(long)(t + 1) * (Mn * Fn) + tid];

    f32x4 aR[2], aZ[2], aHN[2], aXN;
    aR[0] = aR[1] = aZ[0] = aZ[1] = aHN[0] = aHN[1] = aXN = (f32x4){0.f, 0.f, 0.f, 0.f};
#pragma unroll
    for (int ks = 0; ks < 5; ++ks) {
      const int p = ks & 1;
      short8 ah = *(const short8*)&smem_hs[hiC + jl * LDK + ks * 32 + quad * 8];
      short8 al = *(const short8*)&smem_hs[loC + jl * LDK + ks * 32 + quad * 8];
      aR[p] = __builtin_amdgcn_mfma_f32_16x16x32_bf16(ah, frR[ks][0], aR[p], 0, 0, 0);
      aR[p] = __builtin_amdgcn_mfma_f32_16x16x32_bf16(ah, frR[ks][1], aR[p], 0, 0, 0);
      aR[p] = __builtin_amdgcn_mfma_f32_16x16x32_bf16(al, frR[ks][0], aR[p], 0, 0, 0);
      aZ[p] = __builtin_amdgcn_mfma_f32_16x16x32_bf16(ah, frZ[ks][0], aZ[p], 0, 0, 0);
      aZ[p] = __builtin_amdgcn_mfma_f32_16x16x32_bf16(ah, frZ[ks][1], aZ[p], 0, 0, 0);
      aZ[p] = __builtin_amdgcn_mfma_f32_16x16x32_bf16(al, frZ[ks][0], aZ[p], 0, 0, 0);
      if (ks < 4) {
        aHN[p] = __builtin_amdgcn_mfma_f32_16x16x32_bf16(ah, frN[ks][0], aHN[p], 0, 0, 0);
        aHN[p] = __builtin_amdgcn_mfma_f32_16x16x32_bf16(ah, frN[ks][1], aHN[p], 0, 0, 0);
        aHN[p] = __builtin_amdgcn_mfma_f32_16x16x32_bf16(al, frN[ks][0], aHN[p], 0, 0, 0);
      } else {
        aXN = __builtin_amdgcn_mfma_f32_16x16x32_bf16(ah, frXN[0], aXN, 0, 0, 0);
        aXN = __builtin_amdgcn_mfma_f32_16x16x32_bf16(ah, frXN[1], aXN, 0, 0, 0);
        aXN = __builtin_amdgcn_mfma_f32_16x16x32_bf16(al, frXN[0], aXN, 0, 0, 0);
      }
    }

#pragma unroll
    for (int reg = 0; reg < 4; ++reg) {
      float r = sigmoidf_(aR[0][reg] + aR[1][reg] + cr);
      float z = sigmoidf_(aZ[0][reg] + aZ[1][reg] + cz);
      float n = tanhf_(aXN[reg] + cnx + r * (aHN[0][reg] + aHN[1][reg] + cnh));
      float h = (1.f - z) * n + z * hp[reg];
      hp[reg] = h;
      int s = quad * 4 + reg;
      ushort_t hb = bf16_rne(h);
      smem_hs[hiN + s * LDK + j0 + jl] = hb;
      smem_hs[loN + s * LDK + j0 + jl] = bf16_rne(h - bf16_to_f(hb));
    }
    if (tid < 256 && t < Wn - 1) {
      int s = tid >> 4, f = tid & 15;
      ushort_t hb = bf16_rne(xpre);
      smem_hs[hiN + s * LDK + 128 + f] = hb;
      smem_hs[loN + s * LDK + 128 + f] = bf16_rne(xpre - bf16_to_f(hb));
    }
    __syncthreads();
  }

  float* hs_f = (float*)smem_hs;          // 16 x 132 floats
#pragma unroll
  for (int reg = 0; reg < 4; ++reg) {
    int s = quad * 4 + reg;
    float h = hp[reg];
    last_hid[(long)(blk * 16 + s) * Hn + j0 + jl] = h;
    hs_f[s * 132 + j0 + jl] = h;
  }
  __syncthreads();
  {
    int k = tid & 63;
    int part = (tid >> 6) & 1;
    int sg = tid >> 7;
    const float* Wp = part ? W2 : W1;
    float a[4];
    float init = part ? 0.f : b1[k];
    a[0] = a[1] = a[2] = a[3] = init;
    for (int h = 0; h < 128; h += 4) {
      float4 w = *(const float4*)&Wp[k * 128 + h];
#pragma unroll
      for (int rr = 0; rr < 4; ++rr) {
        float4 q = *(const float4*)&hs_f[(sg * 4 + rr) * 132 + h];
        a[rr] += q.x * w.x + q.y * w.y + q.z * w.z + q.w * w.w;
      }
    }
    float* outp = part ? p2 : p1;
#pragma unroll
    for (int rr = 0; rr < 4; ++rr)
      outp[(long)(blk * 16 + sg * 4 + rr) * 64 + k] = a[rr];
  }
}

// ---------------- fused conv + t1; t1 emitted as bf16 hi/lo TRANSPOSED [h][m] ----
__global__ __launch_bounds__(128) void conv_t1_kernel(
    const float* __restrict__ X, const float* __restrict__ conv_w,
    const float* __restrict__ conv_b, const float* __restrict__ convl_w,
    const float* __restrict__ convl_b, const float* __restrict__ gc1_W,
    ushort_t* __restrict__ t1T_hi, ushort_t* __restrict__ t1T_lo) {
  int tid = threadIdx.x;
  int n0 = blockIdx.x * 8;
  int b = n0 >> 9, m0 = n0 & 511;
  __shared__ float xs[8][16][20];
  __shared__ float cw[3200];
  __shared__ float clw[1600];
  __shared__ float rs[8][32];
  for (int idx = tid; idx < 3200; idx += 128) cw[idx] = conv_w[idx];
  for (int idx = tid; idx < 1600; idx += 128) clw[idx] = convl_w[idx];
  for (int w = 0; w < 20; ++w)
    xs[tid >> 4][tid & 15][w] = X[((long)(b * 20 + w) * 512 + m0) * 16 + tid];
  __syncthreads();
  if (tid < 80) {
    int s = tid / 10, k = tid % 10;
    float a0 = conv_b[k];
    float l0 = convl_b[k], l1 = convl_b[k];
    for (int f = 0; f < 16; ++f) {
#pragma unroll
      for (int w = 0; w < 20; ++w) a0 = fmaf(xs[s][f][w], cw[k * 320 + f * 20 + w], a0);
#pragma unroll
      for (int q = 0; q < 10; ++q) {
        float wv = clw[k * 160 + f * 10 + q];
        l0 = fmaf(xs[s][f][2 * q], wv, l0);
        l1 = fmaf(xs[s][f][2 * q + 1], wv, l1);
      }
    }
    rs[s][k * 3 + 0] = reluf_(a0);
    rs[s][k * 3 + 1] = reluf_(l0);
    rs[s][k * 3 + 2] = reluf_(l1);
  }
  __syncthreads();
  float w[30];
#pragma unroll
  for (int q = 0; q < 30; ++q) w[q] = gc1_W[q * 128 + tid];
  long base = ((long)b * 128 + tid) * 512 + m0;
#pragma unroll
  for (int s = 0; s < 8; ++s) {
    float a = 0.f;
#pragma unroll
    for (int q = 0; q < 30; ++q) a = fmaf(rs[s][q], w[q], a);
    ushort_t hb = bf16_rne(a);
    t1T_hi[base + s] = hb;
    t1T_lo[base + s] = bf16_rne(a - bf16_to_f(hb));
  }
}

// ---------------- a_mx raw (32x32 tile) + fused column sum-of-squares ----------------
__global__ __launch_bounds__(256) void amx_kernel(
    const float* __restrict__ p1, const float* __restrict__ p2,
    const float* __restrict__ V, const float* __restrict__ bv,
    float* __restrict__ amx, float* __restrict__ ssq) {
  int tid = threadIdx.x;
  int j0 = blockIdx.x * 32, i0 = blockIdx.y * 32, bz = blockIdx.z;
  __shared__ float p1s[32][68];
  __shared__ float p2s[32][68];
  __shared__ float Vs[64];
  __shared__ float cred[16][33];
  if (tid < 64) Vs[tid] = V[tid];
  {
    int rr = tid >> 3, c0 = (tid & 7) * 8;
    *(float4*)&p1s[rr][c0]     = *(const float4*)&p1[(long)(bz * 512 + j0 + rr) * 64 + c0];
    *(float4*)&p1s[rr][c0 + 4] = *(const float4*)&p1[(long)(bz * 512 + j0 + rr) * 64 + c0 + 4];
    *(float4*)&p2s[rr][c0]     = *(const float4*)&p2[(long)(bz * 512 + i0 + rr) * 64 + c0];
    *(float4*)&p2s[rr][c0 + 4] = *(const float4*)&p2[(long)(bz * 512 + i0 + rr) * 64 + c0 + 4];
  }
  __syncthreads();
  int r0 = tid >> 4, c0 = tid & 15;
  float acc[2][2] = {{0.f, 0.f}, {0.f, 0.f}};
  for (int k = 0; k < 64; ++k) {
    float vj0 = p1s[c0][k], vj1 = p1s[c0 + 16][k];
    float vi0 = p2s[r0][k], vi1 = p2s[r0 + 16][k];
    float vk = Vs[k];
    acc[0][0] = fmaf(eluf_(vj0 + vi0), vk, acc[0][0]);
    acc[0][1] = fmaf(eluf_(vj1 + vi0), vk, acc[0][1]);
    acc[1][0] = fmaf(eluf_(vj0 + vi1), vk, acc[1][0]);
    acc[1][1] = fmaf(eluf_(vj1 + vi1), vk, acc[1][1]);
  }
  float bvv = bv[0];
  float s2[2] = {0.f, 0.f};
#pragma unroll
  for (int a = 0; a < 2; ++a)
#pragma unroll
    for (int c = 0; c < 2; ++c) {
      float v = acc[a][c] + bvv;
      amx[((long)(bz * 512 + i0 + r0 + a * 16)) * 512 + j0 + c0 + c * 16] = v;
      s2[c] += v * v;
    }
  cred[r0][c0] = s2[0];
  cred[r0][c0 + 16] = s2[1];
  __syncthreads();
  if (tid < 32) {
    float s = 0.f;
#pragma unroll
    for (int p = 0; p < 16; ++p) s += cred[p][tid];
    atomicAdd(&ssq[bz * 512 + j0 + tid], s);
  }
}

// ---- gemm_cA via split-bf16 MFMA: 64x64 tiles, 512 blocks x 4 waves ----
// (was 128x64 / 256 blocks x 2 waves = 2 waves/CU — latency-exposed)
#define CPK 40
__global__ __launch_bounds__(256, 2) void gemm_cA(
    const float* __restrict__ amx, const ushort_t* __restrict__ WbT_hi,
    const ushort_t* __restrict__ WbT_lo, const float* __restrict__ adj,
    const float* __restrict__ wb, const float* __restrict__ ssq,
    float* __restrict__ A) {
  const int bz = blockIdx.z;
  const int i0 = blockIdx.y * 64;
  const int j0 = blockIdx.x * 64;
  const int tid = threadIdx.x;
  const int wave = tid >> 6;
  const int lane = tid & 63;
  const int quad = lane >> 4, jl = lane & 15;
  const int wm = (wave & 1) * 32, wn = (wave >> 1) * 32;

  __shared__ __align__(16) ushort_t Ahi[64][CPK];
  __shared__ __align__(16) ushort_t Alo[64][CPK];
  __shared__ __align__(16) ushort_t Bhi[64][CPK];
  __shared__ __align__(16) ushort_t Blo[64][CPK];
  __shared__ float rs_s[512];

  const float* Abase = amx + (long)bz * 262144;
  const float* sb = ssq + bz * 512;
  for (int i = tid; i < 512; i += 256)
    rs_s[i] = 1.f / fmaxf(sqrtf(sb[i]), 1e-12f);

  f32x4 acc[2][2];
#pragma unroll
  for (int a = 0; a < 2; ++a)
#pragma unroll
    for (int c = 0; c < 2; ++c) acc[a][c] = (f32x4){0.f, 0.f, 0.f, 0.f};

  for (int kk0 = 0; kk0 < 512; kk0 += 32) {
    __syncthreads();
#pragma unroll
    for (int l = 0; l < 2; ++l) {
      int e = l * 1024 + tid * 4;
      int r = e >> 5, kq = e & 31;
      float4 v = *(const float4*)&Abase[(long)(i0 + r) * 512 + kk0 + kq];
      float4 sc = *(const float4*)&rs_s[kk0 + kq];
      float vv[4] = {v.x * sc.x, v.y * sc.y, v.z * sc.z, v.w * sc.w};
#pragma unroll
      for (int q = 0; q < 4; ++q) {
        ushort_t hb = bf16_rne(vv[q]);
        Ahi[r][kq + q] = hb;
        Alo[r][kq + q] = bf16_rne(vv[q] - bf16_to_f(hb));
      }
    }
    {
      int r = tid >> 2, kc = (tid & 3) * 8;
      *(uint4*)&Bhi[r][kc] = *(const uint4*)&WbT_hi[(long)(j0 + r) * 512 + kk0 + kc];
      *(uint4*)&Blo[r][kc] = *(const uint4*)&WbT_lo[(long)(j0 + r) * 512 + kk0 + kc];
    }
    __syncthreads();
    short8 ah[2], al[2], bh[2], bl[2];
#pragma unroll
    for (int tm = 0; tm < 2; ++tm) {
      ah[tm] = *(const short8*)&Ahi[wm + tm * 16 + jl][quad * 8];
      al[tm] = *(const short8*)&Alo[wm + tm * 16 + jl][quad * 8];
    }
#pragma unroll
    for (int tn = 0; tn < 2; ++tn) {
      bh[tn] = *(const short8*)&Bhi[wn + tn * 16 + jl][quad * 8];
      bl[tn] = *(const short8*)&Blo[wn + tn * 16 + jl][quad * 8];
    }
#pragma unroll
    for (int tm = 0; tm < 2; ++tm)
#pragma unroll
      for (int tn = 0; tn < 2; ++tn) {
        acc[tm][tn] = __builtin_amdgcn_mfma_f32_16x16x32_bf16(ah[tm], bh[tn], acc[tm][tn], 0, 0, 0);
        acc[tm][tn] = __builtin_amdgcn_mfma_f32_16x16x32_bf16(ah[tm], bl[tn], acc[tm][tn], 0, 0, 0);
        acc[tm][tn] = __builtin_amdgcn_mfma_f32_16x16x32_bf16(al[tm], bh[tn], acc[tm][tn], 0, 0, 0);
      }
  }

  const float wbv = wb[0];
#pragma unroll
  for (int tn = 0; tn < 2; ++tn) {
    int j = j0 + wn + tn * 16 + jl;
    float sj = rs_s[j];
#pragma unroll
    for (int tm = 0; tm < 2; ++tm) {
#pragma unroll
      for (int reg = 0; reg < 4; ++reg) {
        int i = i0 + wm + tm * 16 + quad * 4 + reg;
        long ofs = (long)bz * 262144 + (long)i * 512 + j;
        float c = sigmoidf_(acc[tm][tn][reg] + wbv);
        float am = Abase[(long)i * 512 + j] * sj;
        float ad = adj[(long)i * 512 + j];
        A[ofs] = ad * c + am * (1.f - c);
      }
    }
  }
}

// ---------------- gemm_h1 + fused t2: 512 threads, 8 waves (16-wide N-slices) ----
__global__ __launch_bounds__(512, 1) void gemm_h1t2(
    const float* __restrict__ A, const ushort_t* __restrict__ t1T_hi,
    const ushort_t* __restrict__ t1T_lo, const float* __restrict__ gc1_b,
    const float* __restrict__ gc2_W, float* __restrict__ t2) {
  const int bz = blockIdx.y;
  const int i0 = blockIdx.x * 16;
  const int tid = threadIdx.x;
  const int wave = tid >> 6;
  const int lane = tid & 63;
  const int quad = lane >> 4, jl = lane & 15;

  __shared__ __align__(16) ushort_t Ahi[16][CPK];
  __shared__ __align__(16) ushort_t Alo[16][CPK];
  __shared__ __align__(16) ushort_t Bhi[128][CPK];
  __shared__ __align__(16) ushort_t Blo[128][CPK];
  __shared__ float h1s[16][132];
  __shared__ float gw[1280];

  const float* Ab = A + (long)bz * 262144;
  for (int idx = tid; idx < 1280; idx += 512) gw[idx] = gc2_W[idx];

  f32x4 acc = {0.f, 0.f, 0.f, 0.f};

  for (int kk0 = 0; kk0 < 512; kk0 += 32) {
    __syncthreads();
    {
      int r = tid >> 5, kq = tid & 31;   // 512 threads = 16 x 32 exactly
      float v = Ab[(long)(i0 + r) * 512 + kk0 + kq];
      ushort_t hb = bf16_rne(v);
      Ahi[r][kq] = hb;
      Alo[r][kq] = bf16_rne(v - bf16_to_f(hb));
    }
    {
      int r = tid >> 2, kc = (tid & 3) * 8;  // 512 thr x 8 = 4096 shorts
      *(uint4*)&Bhi[r][kc] = *(const uint4*)&t1T_hi[((long)bz * 128 + r) * 512 + kk0 + kc];
      *(uint4*)&Blo[r][kc] = *(const uint4*)&t1T_lo[((long)bz * 128 + r) * 512 + kk0 + kc];
    }
    __syncthreads();
    short8 ah = *(const short8*)&Ahi[jl][quad * 8];
    short8 al = *(const short8*)&Alo[jl][quad * 8];
    short8 bh = *(const short8*)&Bhi[wave * 16 + jl][quad * 8];
    short8 bl = *(const short8*)&Blo[wave * 16 + jl][quad * 8];
    acc = __builtin_amdgcn_mfma_f32_16x16x32_bf16(ah, bh, acc, 0, 0, 0);
    acc = __builtin_amdgcn_mfma_f32_16x16x32_bf16(ah, bl, acc, 0, 0, 0);
    acc = __builtin_amdgcn_mfma_f32_16x16x32_bf16(al, bh, acc, 0, 0, 0);
  }
  __syncthreads();
  {
    int n = wave * 16 + jl;
    float bb = gc1_b[n];
#pragma unroll
    for (int reg = 0; reg < 4; ++reg) {
      int r = quad * 4 + reg;
      h1s[r][n] = reluf_(acc[reg] + bb);
    }
  }
  __syncthreads();
  if (tid < 160) {
    int r = tid / 10, c = tid % 10;
    float a = 0.f;
#pragma unroll 4
    for (int k = 0; k < 128; ++k) a = fmaf(h1s[r][k], gw[k * 10 + c], a);
    t2[((long)bz * 512 + i0 + r) * 10 + c] = a;
  }
}

// ---------------- spat+readout: BM=8, 512 blocks (2 blocks/CU, 8 waves/CU) ----
__global__ __launch_bounds__(256) void spat_readout(
    const float* __restrict__ A, const float* __restrict__ t2,
    const float* __restrict__ gc2_b, const float* __restrict__ last_hid,
    const float* __restrict__ out_W, const float* __restrict__ out_b,
    const float* __restrict__ Y, float* __restrict__ d_out) {
  int tid = threadIdx.x;
  int bz = blockIdx.y;
  int i0 = blockIdx.x * 8;
  __shared__ float t2s[5120];
  __shared__ float wS[138];
  __shared__ float osps[8][12];
  for (int idx = tid; idx < 5120; idx += 256) t2s[idx] = t2[(long)bz * 5120 + idx];
  for (int idx = tid; idx < 138; idx += 256) wS[idx] = out_W[idx];
  __syncthreads();
  int r = tid >> 5, sk = tid & 31;
  const float* Arow = A + (long)bz * 262144 + (long)(i0 + r) * 512;
  float acc[10] = {0, 0, 0, 0, 0, 0, 0, 0, 0, 0};
  for (int k = sk; k < 512; k += 32) {
    float av = Arow[k];
    const float* tp = &t2s[k * 10];
#pragma unroll
    for (int c = 0; c < 10; ++c) acc[c] = fmaf(av, tp[c], acc[c]);
  }
#pragma unroll
  for (int off = 16; off; off >>= 1)
#pragma unroll
    for (int c = 0; c < 10; ++c) acc[c] += __shfl_xor(acc[c], off);
  if (sk == 0) {
#pragma unroll
    for (int c = 0; c < 10; ++c) osps[r][c] = reluf_(acc[c] + gc2_b[c]);
  }
  __syncthreads();
  float l = 0.f;
  if (tid < 8) {
    int gid = bz * 512 + i0 + tid;
    float y = out_b[0];
#pragma unroll
    for (int k = 0; k < 10; ++k) y = fmaf(osps[tid][k], wS[k], y);
    const float* hp = &last_hid[(long)gid * 128];
    for (int h = 0; h < 128; h += 4) {
      float4 hv = *(const float4*)&hp[h];
      y = fmaf(hv.x, wS[10 + h + 0], y);
      y = fmaf(hv.y, wS[10 + h + 1], y);
      y = fmaf(hv.z, wS[10 + h + 2], y);
      y = fmaf(hv.w, wS[10 + h + 3], y);
    }
    d_out[1 + gid] = sigmoidf_(y);
    l = fmaxf(y, 0.f) + log1pf(__expf(-fabsf(y))) - Y[gid] * y;
  }
  if (tid < 64) {
#pragma unroll
    for (int off = 4; off; off >>= 1) l += __shfl_down(l, off);
    if (tid == 0) atomicAdd(d_out, l * (1.0f / 4096.f));
  }
}

// ---------------- launcher ----------------
extern "C" void kernel_launch(void* const* d_in, const int* in_sizes, int n_in,
                              void* d_out, int out_size, void* d_ws, size_t ws_size,
                              hipStream_t stream) {
  const float* X       = (const float*)d_in[0];
  const float* Y       = (const float*)d_in[1];
  const float* adj     = (const float*)d_in[2];
  const float* V       = (const float*)d_in[3];
  const float* bv      = (const float*)d_in[4];
  const float* W1      = (const float*)d_in[5];
  const float* b1      = (const float*)d_in[6];
  const float* W2      = (const float*)d_in[7];
  const float* Wb      = (const float*)d_in[8];
  const float* wb      = (const float*)d_in[9];
  const float* conv_w  = (const float*)d_in[10];
  const float* conv_b  = (const float*)d_in[11];
  const float* convl_w = (const float*)d_in[12];
  const float* convl_b = (const float*)d_in[13];
  const float* gWih    = (const float*)d_in[14];
  const float* gWhh    = (const float*)d_in[15];
  const float* gbih    = (const float*)d_in[16];
  const float* gbhh    = (const float*)d_in[17];
  const float* gc1_W   = (const float*)d_in[18];
  const float* gc1_b   = (const float*)d_in[19];
  const float* gc2_W   = (const float*)d_in[20];
  const float* gc2_b   = (const float*)d_in[21];
  const float* out_W   = (const float*)d_in[22];
  const float* out_b   = (const float*)d_in[23];
  float* out = (float*)d_out;

  float* ws = (float*)d_ws;
  float* lhid  = ws; ws += 524288;
  float* p1    = ws; ws += 262144;
  float* p2    = ws; ws += 262144;
  float* amx   = ws; ws += 2097152;
  float* ssq   = ws; ws += 4096;
  float* Abuf  = ws; ws += 2097152;
  float* t2    = ws; ws += 40960;
  float* Bpkf  = ws; ws += 122880;   // 245760 ushorts (GRU pack)
  float* WbTf  = ws; ws += 262144;   // 2 x 262144 ushorts
  float* t1Tf  = ws; ws += 524288;   // 2 x 524288 ushorts
  if (ws_size < (size_t)(ws - (float*)d_ws) * sizeof(float)) return;
  ushort_t* Bpack  = (ushort_t*)Bpkf;
  ushort_t* WbT_hi = (ushort_t*)WbTf;
  ushort_t* WbT_lo = WbT_hi + 262144;
  ushort_t* t1T_hi = (ushort_t*)t1Tf;
  ushort_t* t1T_lo = t1T_hi + 524288;

  pack_kernel<<<304, 256, 0, stream>>>(gWhh, gWih, Wb, Bpack, WbT_hi, WbT_lo,
                                       ssq, out);
  gru_kernel<<<256, 512, 0, stream>>>(X, Bpack, gbih, gbhh, W1, W2, b1,
                                      lhid, p1, p2);
  conv_t1_kernel<<<512, 128, 0, stream>>>(X, conv_w, conv_b, convl_w, convl_b,
                                          gc1_W, t1T_hi, t1T_lo);
  amx_kernel<<<dim3(16, 16, 8), 256, 0, stream>>>(p1, p2, V, bv, amx, ssq);
  gemm_cA<<<dim3(8, 8, 8), 256, 0, stream>>>(amx, WbT_hi, WbT_lo, adj, wb,
                                             ssq, Abuf);
  gemm_h1t2<<<dim3(32, 8), 512, 0, stream>>>(Abuf, t1T_hi, t1T_lo, gc1_b,
                                             gc2_W, t2);
  spat_readout<<<dim3(64, 8), 256, 0, stream>>>(Abuf, t2, gc2_b, lhid,
                                                out_W, out_b, Y, out);
}